// Round 7
// baseline (266.057 us; speedup 1.0000x reference)
//
#include <hip/hip_runtime.h>

#define GG    300
#define NPTS  524288
#define CDEN  16
#define CAPP  48
#define ADIM  27
#define KTOT  144
#define TK    72      // LDS A row stride in bf16: cols 0..47 data, 48..63 zero, 64..71 pad
#define NBUCK 32768   // 15-bit Morton buckets
#define NBLK  (NPTS/256)
#define NBLK64 (NPTS/64)
#define CHUNK64 (NBLK64/8)
#define TPBLK ((3*GG*GG + 255)/256)   // 1055

typedef unsigned int u32;
typedef unsigned short u16;
typedef __attribute__((ext_vector_type(8))) short s16x8;
typedef __attribute__((ext_vector_type(4))) float f32x4;

__device__ __forceinline__ u16 f2bf(float f){
  u32 u = __float_as_uint(f);
  u32 r = u + 0x7FFFu + ((u >> 16) & 1u);   // RNE
  return (u16)(r >> 16);
}
__device__ __forceinline__ float bflo(u32 u){ return __uint_as_float(u << 16); }
__device__ __forceinline__ float bfhi(u32 u){ return __uint_as_float(u & 0xFFFF0000u); }

struct IdxW { int i0, i1; float f; };
__device__ __forceinline__ IdxW idxw(float c){
  float x  = (c + 1.0f) * 0.5f * (float)(GG - 1);
  float x0 = floorf(x);
  IdxW r;
  r.f = x - x0;
  int i0 = (int)x0;
  i0 = i0 < 0 ? 0 : (i0 > GG-1 ? GG-1 : i0);
  int i1 = i0 + 1; if (i1 > GG-1) i1 = GG-1;
  r.i0 = i0; r.i1 = i1;
  return r;
}
__device__ __forceinline__ int cell_of(float c){
  float x = (c + 1.0f) * 0.5f * (float)(GG - 1);
  int i = (int)floorf(x);
  return i < 0 ? 0 : (i > GG-1 ? GG-1 : i);
}
__device__ __forceinline__ u32 spread5(u32 v){
  v &= 0x1F;
  v = (v | (v << 8)) & 0x100F;
  v = (v | (v << 4)) & 0x10C3;
  v = (v | (v << 2)) & 0x1249;
  return v;
}

// sample 8 channels: bilinear plane * linear line -> ft[0..7]
__device__ __forceinline__ void sample8(const u16* P00, const u16* P01,
    const u16* P10, const u16* P11, const u16* L0, const u16* L1,
    float w00, float w01, float w10, float w11, float fd, float* ft)
{
  uint4 u00 = *(const uint4*)P00;
  uint4 u01 = *(const uint4*)P01;
  uint4 u10 = *(const uint4*)P10;
  uint4 u11 = *(const uint4*)P11;
  uint4 ul0 = *(const uint4*)L0;
  uint4 ul1 = *(const uint4*)L1;
  u32 a00[4]={u00.x,u00.y,u00.z,u00.w};
  u32 a01[4]={u01.x,u01.y,u01.z,u01.w};
  u32 a10[4]={u10.x,u10.y,u10.z,u10.w};
  u32 a11[4]={u11.x,u11.y,u11.z,u11.w};
  u32 al0[4]={ul0.x,ul0.y,ul0.z,ul0.w};
  u32 al1[4]={ul1.x,ul1.y,ul1.z,ul1.w};
  #pragma unroll
  for (int i = 0; i < 4; i++){
    float plo = w00*bflo(a00[i]) + w01*bflo(a01[i]) + w10*bflo(a10[i]) + w11*bflo(a11[i]);
    float phi = w00*bfhi(a00[i]) + w01*bfhi(a01[i]) + w10*bfhi(a10[i]) + w11*bfhi(a11[i]);
    float l0l = bflo(al0[i]), l1l = bflo(al1[i]);
    float l0h = bfhi(al0[i]), l1h = bfhi(al1[i]);
    ft[2*i+0] = plo * (l0l + fd*(l1l - l0l));
    ft[2*i+1] = phi * (l0h + fd*(l1h - l0h));
  }
}

// ---- device helpers for fused prep ----
template<int C>
__device__ __forceinline__ void do_transpose(const float* __restrict__ in,
                                             u16* __restrict__ out, int cell){
  if (cell >= 3*GG*GG) return;
  int p   = cell / (GG*GG);
  int rem = cell - p*(GG*GG);
  u16 tmp[C];
  #pragma unroll
  for (int c = 0; c < C; c++)
    tmp[c] = f2bf(in[((size_t)(p*C + c))*(GG*GG) + rem]);
  uint4* o = (uint4*)(out + (size_t)cell*C);
  #pragma unroll
  for (int v = 0; v < C/8; v++){
    uint4 q;
    q.x = (u32)tmp[v*8+0] | ((u32)tmp[v*8+1] << 16);
    q.y = (u32)tmp[v*8+2] | ((u32)tmp[v*8+3] << 16);
    q.z = (u32)tmp[v*8+4] | ((u32)tmp[v*8+5] << 16);
    q.w = (u32)tmp[v*8+6] | ((u32)tmp[v*8+7] << 16);
    o[v] = q;
  }
}

// ---- fused prep: transposes + lines + B-frags + Morton histogram/keys ----
__global__ __launch_bounds__(256) void prep_all(
    const float* __restrict__ dplane, const float* __restrict__ aplane,
    const float* __restrict__ dline,  const float* __restrict__ aline,
    const float* __restrict__ W,      const float* __restrict__ xyz,
    u16* __restrict__ dpt, u16* __restrict__ apt,
    u16* __restrict__ dlt, u16* __restrict__ alt,
    uint4* __restrict__ Bfr, u32* __restrict__ hist, u16* __restrict__ keys)
{
  const int b = blockIdx.x;
  const int tid = threadIdx.x;
  if (b < TPBLK){
    do_transpose<CDEN>(dplane, dpt, b*256 + tid);
  } else if (b < 2*TPBLK){
    do_transpose<CAPP>(aplane, apt, (b - TPBLK)*256 + tid);
  } else if (b < 2*TPBLK + 4){
    int t = (b - 2*TPBLK)*256 + tid;
    if (t < 3*GG){
      int p = t / GG, d = t - p*GG;
      #pragma unroll
      for (int c = 0; c < CDEN; c++) dlt[t*CDEN + c] = f2bf(dline[(p*CDEN + c)*GG + d]);
      #pragma unroll
      for (int c = 0; c < CAPP; c++) alt[t*CAPP + c] = f2bf(aline[(p*CAPP + c)*GG + d]);
    }
  } else if (b < 2*TPBLK + 7){
    int t = (b - (2*TPBLK + 4))*256 + tid;
    if (t < 3*2*2*64){
      int lane = t & 63;
      int st = (t >> 6) & 1;
      int nt = (t >> 7) & 1;
      int p  = t >> 8;
      int a  = nt*16 + (lane & 15);
      int kb = st*32 + ((lane >> 4) * 8);
      u32 d[4];
      #pragma unroll
      for (int j2 = 0; j2 < 4; j2++){
        int k0 = kb + 2*j2, k1 = k0 + 1;
        u32 lo = (a < ADIM && k0 < 48) ? (u32)f2bf(W[a*KTOT + p*48 + k0]) : 0u;
        u32 hi = (a < ADIM && k1 < 48) ? (u32)f2bf(W[a*KTOT + p*48 + k1]) : 0u;
        d[j2] = lo | (hi << 16);
      }
      Bfr[t] = make_uint4(d[0], d[1], d[2], d[3]);
    }
  } else {
    int n = (b - (2*TPBLK + 7))*256 + tid;
    float X = xyz[3*n+0], Y = xyz[3*n+1], Z = xyz[3*n+2];
    u32 bx = (u32)(cell_of(X) >> 4);
    u32 by = (u32)(cell_of(Y) >> 4);
    u32 bz = (u32)(cell_of(Z) >> 4);
    u32 key = spread5(bx) | (spread5(by) << 1) | (spread5(bz) << 2);
    keys[n] = (u16)key;
    atomicAdd(&hist[key], 1u);
  }
}

__global__ __launch_bounds__(1024) void scan_hist(const u32* __restrict__ hist,
                                                  u32* __restrict__ offs){
  __shared__ u32 part[1024];
  const int t = threadIdx.x;
  u32 local[32];
  u32 sum = 0;
  #pragma unroll
  for (int i = 0; i < 32; i++){ local[i] = sum; sum += hist[t*32 + i]; }
  part[t] = sum;
  __syncthreads();
  for (int off = 1; off < 1024; off <<= 1){
    u32 v = (t >= off) ? part[t - off] : 0;
    __syncthreads();
    part[t] += v;
    __syncthreads();
  }
  u32 base = (t > 0) ? part[t-1] : 0;
  #pragma unroll
  for (int i = 0; i < 32; i++) offs[t*32 + i] = base + local[i];
}

// scatter: pack {x,y,z,orig_idx} into one float4 per sorted slot
__global__ __launch_bounds__(256) void scatter_pts(const float* __restrict__ xyz,
                                                   const u16* __restrict__ keys,
                                                   u32* __restrict__ offs,
                                                   float4* __restrict__ xyzq){
  int n = blockIdx.x*256 + threadIdx.x;
  u32 pos = atomicAdd(&offs[keys[n]], 1u);
  float4 q;
  q.x = xyz[3*n+0]; q.y = xyz[3*n+1]; q.z = xyz[3*n+2];
  q.w = __int_as_float(n);
  xyzq[pos] = q;
}

// ---- main: fused sampling + per-wave MFMA GEMM. ONE WAVE PER BLOCK ----
// R7: no memory fences, plane loop fully unrolled -> compiler may hoist
// plane p+1's gathers under plane p's pack/MFMA (latency hiding). Correct
// without fences: A-tile writes/reads are same-object (alias-ordered) and
// per-wave LDS ops are in-order in HW; LDS is wave-private.
// Empirically (256,4) launch_bounds caps VGPR at 64 and spills; keep plain.
template<bool SORTED>
__global__ __launch_bounds__(64) void sample_mfma(
    const float4* __restrict__ xyzq,  // sorted {x,y,z,idx} (SORTED)
    const float* __restrict__ xyz,    // original (fallback)
    const u16*  __restrict__ dpt,     // [3][G][G][16]
    const u16*  __restrict__ apt,     // [3][G][G][48]
    const u16*  __restrict__ dlt,     // [3][G][16]
    const u16*  __restrict__ alt,     // [3][G][48]
    const uint4* __restrict__ Bfr,    // [3][2][2][64]
    float* __restrict__ outv)         // [N] sigma ++ [N][27] app
{
  __shared__ __align__(16) u16 Asm[64*TK];   // 9216 B, wave-private
  const int lane = threadIdx.x;
  int bid = blockIdx.x;
  if (SORTED) bid = (bid & 7)*CHUNK64 + (bid >> 3);   // XCD-chunked Morton octants
  const int n = bid*64 + lane;

  float X, Y, Z; int pn;
  if (SORTED){
    float4 q = xyzq[n];
    X = q.x; Y = q.y; Z = q.z; pn = __float_as_int(q.w);
  } else {
    X = xyz[3*n+0]; Y = xyz[3*n+1]; Z = xyz[3*n+2]; pn = n;
  }

  u16* Arow = Asm + lane*TK;
  const u16* Awave = Asm;

  float sigma = 0.f;
  f32x4 acc[4][2];
  #pragma unroll
  for (int t = 0; t < 4; t++){
    acc[t][0] = (f32x4){0.f,0.f,0.f,0.f};
    acc[t][1] = (f32x4){0.f,0.f,0.f,0.f};
  }

  uint4 z4 = make_uint4(0,0,0,0);
  *(uint4*)(Arow + 48) = z4;
  *(uint4*)(Arow + 56) = z4;

  #pragma unroll
  for (int p = 0; p < 3; p++){
    const float dc = (p==0) ? Z : ((p==1) ? Y : X);
    const float hc = (p==0) ? Y : Z;

    uint4 b00 = Bfr[(p*4 + 0)*64 + lane];
    uint4 b01 = Bfr[(p*4 + 1)*64 + lane];
    uint4 b10 = Bfr[(p*4 + 2)*64 + lane];
    uint4 b11 = Bfr[(p*4 + 3)*64 + lane];

    IdxW D = idxw(dc), H = idxw(hc);
    const float fd = D.f, fh = H.f;
    const float w00 = (1.f-fd)*(1.f-fh), w01 = (1.f-fd)*fh;
    const float w10 = fd*(1.f-fh),       w11 = fd*fh;

    { // density -> sigma
      const u16* P00 = dpt + ((p*GG+D.i0)*GG+H.i0)*CDEN;
      const u16* P01 = dpt + ((p*GG+D.i0)*GG+H.i1)*CDEN;
      const u16* P10 = dpt + ((p*GG+D.i1)*GG+H.i0)*CDEN;
      const u16* P11 = dpt + ((p*GG+D.i1)*GG+H.i1)*CDEN;
      const u16* L0  = dlt + (p*GG+D.i0)*CDEN;
      const u16* L1  = dlt + (p*GG+D.i1)*CDEN;
      #pragma unroll
      for (int g = 0; g < 2; g++){
        float ft[8];
        sample8(P00+g*8, P01+g*8, P10+g*8, P11+g*8, L0+g*8, L1+g*8,
                w00,w01,w10,w11, fd, ft);
        sigma += ((ft[0]+ft[1])+(ft[2]+ft[3])) + ((ft[4]+ft[5])+(ft[6]+ft[7]));
      }
    }

    { // app feats -> LDS A tile (unroll 2: bounded live ranges, no spill)
      const u16* P00 = apt + ((p*GG+D.i0)*GG+H.i0)*CAPP;
      const u16* P01 = apt + ((p*GG+D.i0)*GG+H.i1)*CAPP;
      const u16* P10 = apt + ((p*GG+D.i1)*GG+H.i0)*CAPP;
      const u16* P11 = apt + ((p*GG+D.i1)*GG+H.i1)*CAPP;
      const u16* L0  = alt + (p*GG+D.i0)*CAPP;
      const u16* L1  = alt + (p*GG+D.i1)*CAPP;
      #pragma unroll 2
      for (int g = 0; g < 6; g++){
        float ft[8];
        sample8(P00+g*8, P01+g*8, P10+g*8, P11+g*8, L0+g*8, L1+g*8,
                w00,w01,w10,w11, fd, ft);
        uint4 d;
        d.x = (u32)f2bf(ft[0]) | ((u32)f2bf(ft[1]) << 16);
        d.y = (u32)f2bf(ft[2]) | ((u32)f2bf(ft[3]) << 16);
        d.z = (u32)f2bf(ft[4]) | ((u32)f2bf(ft[5]) << 16);
        d.w = (u32)f2bf(ft[6]) | ((u32)f2bf(ft[7]) << 16);
        *(uint4*)(Arow + g*8) = d;
      }
    }

    #pragma unroll
    for (int t = 0; t < 4; t++){
      const u16* ab = Awave + (t*16 + (lane & 15))*TK + ((lane >> 4) * 8);
      s16x8 a0 = __builtin_bit_cast(s16x8, *(const uint4*)ab);
      s16x8 a1 = __builtin_bit_cast(s16x8, *(const uint4*)(ab + 32));
      acc[t][0] = __builtin_amdgcn_mfma_f32_16x16x32_bf16(a0, __builtin_bit_cast(s16x8,b00), acc[t][0], 0,0,0);
      acc[t][0] = __builtin_amdgcn_mfma_f32_16x16x32_bf16(a1, __builtin_bit_cast(s16x8,b01), acc[t][0], 0,0,0);
      acc[t][1] = __builtin_amdgcn_mfma_f32_16x16x32_bf16(a0, __builtin_bit_cast(s16x8,b10), acc[t][1], 0,0,0);
      acc[t][1] = __builtin_amdgcn_mfma_f32_16x16x32_bf16(a1, __builtin_bit_cast(s16x8,b11), acc[t][1], 0,0,0);
    }
  }

  outv[pn] = sigma;

  float* ao = outv + NPTS;
  #pragma unroll
  for (int t = 0; t < 4; t++){
    #pragma unroll
    for (int nt = 0; nt < 2; nt++){
      int a = nt*16 + (lane & 15);
      #pragma unroll
      for (int r = 0; r < 4; r++){
        int src = t*16 + (lane >> 4)*4 + r;   // point index within wave
        int pr = __shfl(pn, src);
        if (a < ADIM)
          ao[(size_t)pr*ADIM + a] = acc[t][nt][r];
      }
    }
  }
}

// ---- fallback: direct fp32 sampling ----
__global__ void sample_naive(const float* __restrict__ xyz,
    const float* __restrict__ dp, const float* __restrict__ dl,
    const float* __restrict__ ap, const float* __restrict__ al,
    const float* __restrict__ W,  float* __restrict__ outv)
{
  int n = blockIdx.x*blockDim.x + threadIdx.x;
  if (n >= NPTS) return;
  float X = xyz[3*n], Y = xyz[3*n+1], Z = xyz[3*n+2];
  float dco[3] = {Z, Y, X};
  float hco[3] = {Y, Z, Z};
  float sigma = 0.f, acc[ADIM];
  for (int a = 0; a < ADIM; a++) acc[a] = 0.f;
  for (int p = 0; p < 3; p++){
    IdxW D = idxw(dco[p]), H = idxw(hco[p]);
    float fd = D.f, fh = H.f;
    float w00=(1.f-fd)*(1.f-fh), w01=(1.f-fd)*fh, w10=fd*(1.f-fh), w11=fd*fh;
    for (int c = 0; c < CDEN; c++){
      const float* pl = dp + (size_t)(p*CDEN + c)*GG*GG;
      float pv = w00*pl[D.i0*GG+H.i0] + w01*pl[D.i0*GG+H.i1]
               + w10*pl[D.i1*GG+H.i0] + w11*pl[D.i1*GG+H.i1];
      const float* ll = dl + (p*CDEN + c)*GG;
      sigma += pv * (ll[D.i0] + fd*(ll[D.i1] - ll[D.i0]));
    }
    for (int c = 0; c < CAPP; c++){
      const float* pl = ap + (size_t)(p*CAPP + c)*GG*GG;
      float pv = w00*pl[D.i0*GG+H.i0] + w01*pl[D.i0*GG+H.i1]
               + w10*pl[D.i1*GG+H.i0] + w11*pl[D.i1*GG+H.i1];
      const float* ll = al + (p*CAPP + c)*GG;
      float ft = pv * (ll[D.i0] + fd*(ll[D.i1] - ll[D.i0]));
      int k = p*CAPP + c;
      for (int a = 0; a < ADIM; a++) acc[a] = fmaf(ft, W[a*KTOT + k], acc[a]);
    }
  }
  outv[n] = sigma;
  for (int a = 0; a < ADIM; a++) outv[NPTS + (size_t)n*ADIM + a] = acc[a];
}

extern "C" void kernel_launch(void* const* d_in, const int* in_sizes, int n_in,
                              void* d_out, int out_size, void* d_ws, size_t ws_size,
                              hipStream_t stream){
  const float* xyz    = (const float*)d_in[0];
  const float* dplane = (const float*)d_in[1];
  const float* dline  = (const float*)d_in[2];
  const float* aplane = (const float*)d_in[3];
  const float* aline  = (const float*)d_in[4];
  const float* W      = (const float*)d_in[5];
  float* outv = (float*)d_out;

  const size_t sz_dpt  = (size_t)3*GG*GG*CDEN*2;
  const size_t sz_apt  = (size_t)3*GG*GG*CAPP*2;
  const size_t sz_dlt  = (size_t)3*GG*CDEN*2;
  const size_t sz_alt  = (size_t)3*GG*CAPP*2;
  const size_t sz_bfr  = (size_t)3*2*2*64*16;
  const size_t sz_hist = (size_t)NBUCK*4;
  const size_t sz_offs = (size_t)NBUCK*4;
  const size_t sz_keys = (size_t)NPTS*2;
  const size_t sz_xyzq = (size_t)NPTS*16;

  const size_t off_apt  = sz_dpt;
  const size_t off_dlt  = off_apt + sz_apt;
  const size_t off_alt  = off_dlt + sz_dlt;
  const size_t off_bfr  = off_alt + sz_alt;
  const size_t off_hist = off_bfr + sz_bfr;
  const size_t off_offs = off_hist + sz_hist;
  const size_t off_keys = off_offs + sz_offs;
  const size_t off_xyzq = off_keys + sz_keys;
  const size_t need_tab  = off_hist;
  const size_t need_full = off_xyzq + sz_xyzq;

  if (ws_size < need_tab){
    sample_naive<<<(NPTS+255)/256, 256, 0, stream>>>(xyz, dplane, dline, aplane, aline, W, outv);
    return;
  }

  u16*   dpt = (u16*)((char*)d_ws);
  u16*   apt = (u16*)((char*)d_ws + off_apt);
  u16*   dlt = (u16*)((char*)d_ws + off_dlt);
  u16*   alt = (u16*)((char*)d_ws + off_alt);
  uint4* bfr = (uint4*)((char*)d_ws + off_bfr);

  if (ws_size < need_full){
    prep_all<<<2*TPBLK + 7, 256, 0, stream>>>(dplane, aplane, dline, aline, W, xyz,
                                              dpt, apt, dlt, alt, bfr, nullptr, nullptr);
    sample_mfma<false><<<NBLK64, 64, 0, stream>>>(nullptr, xyz, dpt, apt, dlt, alt, bfr, outv);
    return;
  }

  u32*    hist = (u32*)((char*)d_ws + off_hist);
  u32*    offs = (u32*)((char*)d_ws + off_offs);
  u16*    keys = (u16*)((char*)d_ws + off_keys);
  float4* xyzq = (float4*)((char*)d_ws + off_xyzq);

  hipMemsetAsync(hist, 0, sz_hist, stream);
  prep_all<<<2*TPBLK + 7 + NBLK, 256, 0, stream>>>(dplane, aplane, dline, aline, W, xyz,
                                                   dpt, apt, dlt, alt, bfr, hist, keys);
  scan_hist<<<1, 1024, 0, stream>>>(hist, offs);
  scatter_pts<<<NBLK, 256, 0, stream>>>(xyz, keys, offs, xyzq);
  sample_mfma<true><<<NBLK64, 64, 0, stream>>>(xyzq, nullptr, dpt, apt, dlt, alt, bfr, outv);
}

// Round 9
// 254.199 us; speedup vs baseline: 1.0466x; 1.0466x over previous
//
#include <hip/hip_runtime.h>

#define GG    300
#define NPTS  524288
#define CDEN  16
#define CAPP  48
#define ADIM  27
#define KTOT  144
#define TK    72      // LDS A row stride in bf16: cols 0..47 data, 48..63 zero, 64..71 pad
#define NBUCK 32768   // 15-bit Morton buckets
#define NBLK  (NPTS/256)
#define NBLK64 (NPTS/64)
#define CHUNK64 (NBLK64/8)
#define TPBLK ((3*GG*GG + 255)/256)   // 1055

typedef unsigned int u32;
typedef unsigned short u16;
typedef __attribute__((ext_vector_type(8))) short s16x8;
typedef __attribute__((ext_vector_type(4))) float f32x4;

__device__ __forceinline__ u16 f2bf(float f){
  u32 u = __float_as_uint(f);
  u32 r = u + 0x7FFFu + ((u >> 16) & 1u);   // RNE
  return (u16)(r >> 16);
}
__device__ __forceinline__ float bflo(u32 u){ return __uint_as_float(u << 16); }
__device__ __forceinline__ float bfhi(u32 u){ return __uint_as_float(u & 0xFFFF0000u); }

struct IdxW { int i0, i1; float f; };
__device__ __forceinline__ IdxW idxw(float c){
  float x  = (c + 1.0f) * 0.5f * (float)(GG - 1);
  float x0 = floorf(x);
  IdxW r;
  r.f = x - x0;
  int i0 = (int)x0;
  i0 = i0 < 0 ? 0 : (i0 > GG-1 ? GG-1 : i0);
  int i1 = i0 + 1; if (i1 > GG-1) i1 = GG-1;
  r.i0 = i0; r.i1 = i1;
  return r;
}
__device__ __forceinline__ int cell_of(float c){
  float x = (c + 1.0f) * 0.5f * (float)(GG - 1);
  int i = (int)floorf(x);
  return i < 0 ? 0 : (i > GG-1 ? GG-1 : i);
}
__device__ __forceinline__ u32 spread5(u32 v){
  v &= 0x1F;
  v = (v | (v << 8)) & 0x100F;
  v = (v | (v << 4)) & 0x10C3;
  v = (v | (v << 2)) & 0x1249;
  return v;
}

// sample 8 channels: bilinear plane * linear line -> ft[0..7]
__device__ __forceinline__ void sample8(const u16* P00, const u16* P01,
    const u16* P10, const u16* P11, const u16* L0, const u16* L1,
    float w00, float w01, float w10, float w11, float fd, float* ft)
{
  uint4 u00 = *(const uint4*)P00;
  uint4 u01 = *(const uint4*)P01;
  uint4 u10 = *(const uint4*)P10;
  uint4 u11 = *(const uint4*)P11;
  uint4 ul0 = *(const uint4*)L0;
  uint4 ul1 = *(const uint4*)L1;
  u32 a00[4]={u00.x,u00.y,u00.z,u00.w};
  u32 a01[4]={u01.x,u01.y,u01.z,u01.w};
  u32 a10[4]={u10.x,u10.y,u10.z,u10.w};
  u32 a11[4]={u11.x,u11.y,u11.z,u11.w};
  u32 al0[4]={ul0.x,ul0.y,ul0.z,ul0.w};
  u32 al1[4]={ul1.x,ul1.y,ul1.z,ul1.w};
  #pragma unroll
  for (int i = 0; i < 4; i++){
    float plo = w00*bflo(a00[i]) + w01*bflo(a01[i]) + w10*bflo(a10[i]) + w11*bflo(a11[i]);
    float phi = w00*bfhi(a00[i]) + w01*bfhi(a01[i]) + w10*bfhi(a10[i]) + w11*bfhi(a11[i]);
    float l0l = bflo(al0[i]), l1l = bflo(al1[i]);
    float l0h = bfhi(al0[i]), l1h = bfhi(al1[i]);
    ft[2*i+0] = plo * (l0l + fd*(l1l - l0l));
    ft[2*i+1] = phi * (l0h + fd*(l1h - l0h));
  }
}

// ---- fused prep: LDS-staged transposes + lines + B-frags + Morton hist/keys ----
// Transposes staged through LDS so global WRITES are per-instruction coalesced
// (old path: each thread stored 96B at 96B stride -> 64 lanes scattered over
// ~96 cache lines per store instruction). LDS rows padded (52/20 u16) for
// 8B alignment + 2-way-max bank conflicts (2-way is free, m136).
__global__ __launch_bounds__(256) void prep_all(
    const float* __restrict__ dplane, const float* __restrict__ aplane,
    const float* __restrict__ dline,  const float* __restrict__ aline,
    const float* __restrict__ W,      const float* __restrict__ xyz,
    u16* __restrict__ dpt, u16* __restrict__ apt,
    u16* __restrict__ dlt, u16* __restrict__ alt,
    uint4* __restrict__ Bfr, u32* __restrict__ hist, u16* __restrict__ keys)
{
  __shared__ __align__(16) u16 T[256*52];   // 26.6 KB staging
  const int b = blockIdx.x;
  const int tid = threadIdx.x;
  if (b < TPBLK){
    // density plane transpose [3][16][G*G] -> [cell][16]
    const int cell0 = b*256;
    const int ncell = min(256, 3*GG*GG - cell0);
    const int cell  = cell0 + tid;
    if (tid < ncell){
      int p = cell/(GG*GG), rem = cell - p*(GG*GG);
      #pragma unroll
      for (int c = 0; c < CDEN; c++)
        T[tid*20 + c] = f2bf(dplane[((size_t)(p*CDEN+c))*(GG*GG) + rem]);
    }
    __syncthreads();
    uint2* dst = (uint2*)(dpt + (size_t)cell0*CDEN);
    const int nch = ncell*4;                 // 8B chunks (32B/cell)
    #pragma unroll
    for (int k = 0; k < 4; k++){
      int idx = k*256 + tid;
      if (idx < nch){
        int cl = idx >> 2, j = idx & 3;
        dst[idx] = *(const uint2*)(T + cl*20 + j*4);
      }
    }
  } else if (b < 2*TPBLK){
    // app plane transpose [3][48][G*G] -> [cell][48]
    const int cell0 = (b - TPBLK)*256;
    const int ncell = min(256, 3*GG*GG - cell0);
    const int cell  = cell0 + tid;
    if (tid < ncell){
      int p = cell/(GG*GG), rem = cell - p*(GG*GG);
      #pragma unroll
      for (int c = 0; c < CAPP; c++)
        T[tid*52 + c] = f2bf(aplane[((size_t)(p*CAPP+c))*(GG*GG) + rem]);
    }
    __syncthreads();
    uint2* dst = (uint2*)(apt + (size_t)cell0*CAPP);
    const int nch = ncell*12;                // 8B chunks (96B/cell)
    #pragma unroll
    for (int k = 0; k < 12; k++){
      int idx = k*256 + tid;
      if (idx < nch){
        int cl = idx/12, j = idx - cl*12;
        dst[idx] = *(const uint2*)(T + cl*52 + j*4);
      }
    }
  } else if (b < 2*TPBLK + 4){
    int t = (b - 2*TPBLK)*256 + tid;
    if (t < 3*GG){
      int p = t / GG, d = t - p*GG;
      #pragma unroll
      for (int c = 0; c < CDEN; c++) dlt[t*CDEN + c] = f2bf(dline[(p*CDEN + c)*GG + d]);
      #pragma unroll
      for (int c = 0; c < CAPP; c++) alt[t*CAPP + c] = f2bf(aline[(p*CAPP + c)*GG + d]);
    }
  } else if (b < 2*TPBLK + 7){
    int t = (b - (2*TPBLK + 4))*256 + tid;
    if (t < 3*2*2*64){
      int lane = t & 63;
      int st = (t >> 6) & 1;
      int nt = (t >> 7) & 1;
      int p  = t >> 8;
      int a  = nt*16 + (lane & 15);
      int kb = st*32 + ((lane >> 4) * 8);
      u32 d[4];
      #pragma unroll
      for (int j2 = 0; j2 < 4; j2++){
        int k0 = kb + 2*j2, k1 = k0 + 1;
        u32 lo = (a < ADIM && k0 < 48) ? (u32)f2bf(W[a*KTOT + p*48 + k0]) : 0u;
        u32 hi = (a < ADIM && k1 < 48) ? (u32)f2bf(W[a*KTOT + p*48 + k1]) : 0u;
        d[j2] = lo | (hi << 16);
      }
      Bfr[t] = make_uint4(d[0], d[1], d[2], d[3]);
    }
  } else {
    int n = (b - (2*TPBLK + 7))*256 + tid;
    float X = xyz[3*n+0], Y = xyz[3*n+1], Z = xyz[3*n+2];
    u32 bx = (u32)(cell_of(X) >> 4);
    u32 by = (u32)(cell_of(Y) >> 4);
    u32 bz = (u32)(cell_of(Z) >> 4);
    u32 key = spread5(bx) | (spread5(by) << 1) | (spread5(bz) << 2);
    keys[n] = (u16)key;
    atomicAdd(&hist[key], 1u);
  }
}

__global__ __launch_bounds__(1024) void scan_hist(const u32* __restrict__ hist,
                                                  u32* __restrict__ offs){
  __shared__ u32 part[1024];
  const int t = threadIdx.x;
  u32 local[32];
  u32 sum = 0;
  #pragma unroll
  for (int i = 0; i < 32; i++){ local[i] = sum; sum += hist[t*32 + i]; }
  part[t] = sum;
  __syncthreads();
  for (int off = 1; off < 1024; off <<= 1){
    u32 v = (t >= off) ? part[t - off] : 0;
    __syncthreads();
    part[t] += v;
    __syncthreads();
  }
  u32 base = (t > 0) ? part[t-1] : 0;
  #pragma unroll
  for (int i = 0; i < 32; i++) offs[t*32 + i] = base + local[i];
}

// scatter: pack {x,y,z,orig_idx} into one float4 per sorted slot
__global__ __launch_bounds__(256) void scatter_pts(const float* __restrict__ xyz,
                                                   const u16* __restrict__ keys,
                                                   u32* __restrict__ offs,
                                                   float4* __restrict__ xyzq){
  int n = blockIdx.x*256 + threadIdx.x;
  u32 pos = atomicAdd(&offs[keys[n]], 1u);
  float4 q;
  q.x = xyz[3*n+0]; q.y = xyz[3*n+1]; q.z = xyz[3*n+2];
  q.w = __int_as_float(n);
  xyzq[pos] = q;
}

// ---- main: fused sampling + per-wave MFMA GEMM. ONE WAVE PER BLOCK ----
// R6-proven config: plain __launch_bounds__(64). DO NOT add the 2nd
// launch_bounds arg on this hipcc: (256,4) forced 64 VGPR + 400MB spill (R4);
// (64,5) silently miscomputed (R8, absmax 1.6e-2). Kernel is at its
// address-throughput roofline (~144 gather instrs/point ~= 123us model).
template<bool SORTED>
__global__ __launch_bounds__(64) void sample_mfma(
    const float4* __restrict__ xyzq,  // sorted {x,y,z,idx} (SORTED)
    const float* __restrict__ xyz,    // original (fallback)
    const u16*  __restrict__ dpt,     // [3][G][G][16]
    const u16*  __restrict__ apt,     // [3][G][G][48]
    const u16*  __restrict__ dlt,     // [3][G][16]
    const u16*  __restrict__ alt,     // [3][G][48]
    const uint4* __restrict__ Bfr,    // [3][2][2][64]
    float* __restrict__ outv)         // [N] sigma ++ [N][27] app
{
  __shared__ __align__(16) u16 Asm[64*TK];   // 9216 B, wave-private
  const int lane = threadIdx.x;
  int bid = blockIdx.x;
  if (SORTED) bid = (bid & 7)*CHUNK64 + (bid >> 3);   // XCD-chunked Morton octants
  const int n = bid*64 + lane;

  float X, Y, Z; int pn;
  if (SORTED){
    float4 q = xyzq[n];
    X = q.x; Y = q.y; Z = q.z; pn = __float_as_int(q.w);
  } else {
    X = xyz[3*n+0]; Y = xyz[3*n+1]; Z = xyz[3*n+2]; pn = n;
  }

  u16* Arow = Asm + lane*TK;
  const u16* Awave = Asm;

  float sigma = 0.f;
  f32x4 acc[4][2];
  #pragma unroll
  for (int t = 0; t < 4; t++){
    acc[t][0] = (f32x4){0.f,0.f,0.f,0.f};
    acc[t][1] = (f32x4){0.f,0.f,0.f,0.f};
  }

  uint4 z4 = make_uint4(0,0,0,0);
  *(uint4*)(Arow + 48) = z4;
  *(uint4*)(Arow + 56) = z4;

  #pragma unroll 1
  for (int p = 0; p < 3; p++){
    const float dc = (p==0) ? Z : ((p==1) ? Y : X);
    const float hc = (p==0) ? Y : Z;

    uint4 b00 = Bfr[(p*4 + 0)*64 + lane];
    uint4 b01 = Bfr[(p*4 + 1)*64 + lane];
    uint4 b10 = Bfr[(p*4 + 2)*64 + lane];
    uint4 b11 = Bfr[(p*4 + 3)*64 + lane];

    IdxW D = idxw(dc), H = idxw(hc);
    const float fd = D.f, fh = H.f;
    const float w00 = (1.f-fd)*(1.f-fh), w01 = (1.f-fd)*fh;
    const float w10 = fd*(1.f-fh),       w11 = fd*fh;

    { // density -> sigma
      const u16* P00 = dpt + ((p*GG+D.i0)*GG+H.i0)*CDEN;
      const u16* P01 = dpt + ((p*GG+D.i0)*GG+H.i1)*CDEN;
      const u16* P10 = dpt + ((p*GG+D.i1)*GG+H.i0)*CDEN;
      const u16* P11 = dpt + ((p*GG+D.i1)*GG+H.i1)*CDEN;
      const u16* L0  = dlt + (p*GG+D.i0)*CDEN;
      const u16* L1  = dlt + (p*GG+D.i1)*CDEN;
      #pragma unroll
      for (int g = 0; g < 2; g++){
        float ft[8];
        sample8(P00+g*8, P01+g*8, P10+g*8, P11+g*8, L0+g*8, L1+g*8,
                w00,w01,w10,w11, fd, ft);
        sigma += ((ft[0]+ft[1])+(ft[2]+ft[3])) + ((ft[4]+ft[5])+(ft[6]+ft[7]));
      }
    }

    { // app feats -> LDS A tile (unroll 2: bounded live ranges, no spill)
      const u16* P00 = apt + ((p*GG+D.i0)*GG+H.i0)*CAPP;
      const u16* P01 = apt + ((p*GG+D.i0)*GG+H.i1)*CAPP;
      const u16* P10 = apt + ((p*GG+D.i1)*GG+H.i0)*CAPP;
      const u16* P11 = apt + ((p*GG+D.i1)*GG+H.i1)*CAPP;
      const u16* L0  = alt + (p*GG+D.i0)*CAPP;
      const u16* L1  = alt + (p*GG+D.i1)*CAPP;
      #pragma unroll 2
      for (int g = 0; g < 6; g++){
        float ft[8];
        sample8(P00+g*8, P01+g*8, P10+g*8, P11+g*8, L0+g*8, L1+g*8,
                w00,w01,w10,w11, fd, ft);
        uint4 d;
        d.x = (u32)f2bf(ft[0]) | ((u32)f2bf(ft[1]) << 16);
        d.y = (u32)f2bf(ft[2]) | ((u32)f2bf(ft[3]) << 16);
        d.z = (u32)f2bf(ft[4]) | ((u32)f2bf(ft[5]) << 16);
        d.w = (u32)f2bf(ft[6]) | ((u32)f2bf(ft[7]) << 16);
        *(uint4*)(Arow + g*8) = d;
      }
    }

    // compiler-only fence: LDS ops within a wave complete in order in HW.
    asm volatile("" ::: "memory");

    #pragma unroll
    for (int t = 0; t < 4; t++){
      const u16* ab = Awave + (t*16 + (lane & 15))*TK + ((lane >> 4) * 8);
      s16x8 a0 = __builtin_bit_cast(s16x8, *(const uint4*)ab);
      s16x8 a1 = __builtin_bit_cast(s16x8, *(const uint4*)(ab + 32));
      acc[t][0] = __builtin_amdgcn_mfma_f32_16x16x32_bf16(a0, __builtin_bit_cast(s16x8,b00), acc[t][0], 0,0,0);
      acc[t][0] = __builtin_amdgcn_mfma_f32_16x16x32_bf16(a1, __builtin_bit_cast(s16x8,b01), acc[t][0], 0,0,0);
      acc[t][1] = __builtin_amdgcn_mfma_f32_16x16x32_bf16(a0, __builtin_bit_cast(s16x8,b10), acc[t][1], 0,0,0);
      acc[t][1] = __builtin_amdgcn_mfma_f32_16x16x32_bf16(a1, __builtin_bit_cast(s16x8,b11), acc[t][1], 0,0,0);
    }
    asm volatile("" ::: "memory");   // keep next plane's LDS writes below these reads
  }

  outv[pn] = sigma;

  float* ao = outv + NPTS;
  #pragma unroll
  for (int t = 0; t < 4; t++){
    #pragma unroll
    for (int nt = 0; nt < 2; nt++){
      int a = nt*16 + (lane & 15);
      #pragma unroll
      for (int r = 0; r < 4; r++){
        int src = t*16 + (lane >> 4)*4 + r;   // point index within wave
        int pr = __shfl(pn, src);
        if (a < ADIM)
          ao[(size_t)pr*ADIM + a] = acc[t][nt][r];
      }
    }
  }
}

// ---- fallback: direct fp32 sampling ----
__global__ void sample_naive(const float* __restrict__ xyz,
    const float* __restrict__ dp, const float* __restrict__ dl,
    const float* __restrict__ ap, const float* __restrict__ al,
    const float* __restrict__ W,  float* __restrict__ outv)
{
  int n = blockIdx.x*blockDim.x + threadIdx.x;
  if (n >= NPTS) return;
  float X = xyz[3*n], Y = xyz[3*n+1], Z = xyz[3*n+2];
  float dco[3] = {Z, Y, X};
  float hco[3] = {Y, Z, Z};
  float sigma = 0.f, acc[ADIM];
  for (int a = 0; a < ADIM; a++) acc[a] = 0.f;
  for (int p = 0; p < 3; p++){
    IdxW D = idxw(dco[p]), H = idxw(hco[p]);
    float fd = D.f, fh = H.f;
    float w00=(1.f-fd)*(1.f-fh), w01=(1.f-fd)*fh, w10=fd*(1.f-fh), w11=fd*fh;
    for (int c = 0; c < CDEN; c++){
      const float* pl = dp + (size_t)(p*CDEN + c)*GG*GG;
      float pv = w00*pl[D.i0*GG+H.i0] + w01*pl[D.i0*GG+H.i1]
               + w10*pl[D.i1*GG+H.i0] + w11*pl[D.i1*GG+H.i1];
      const float* ll = dl + (p*CDEN + c)*GG;
      sigma += pv * (ll[D.i0] + fd*(ll[D.i1] - ll[D.i0]));
    }
    for (int c = 0; c < CAPP; c++){
      const float* pl = ap + (size_t)(p*CAPP + c)*GG*GG;
      float pv = w00*pl[D.i0*GG+H.i0] + w01*pl[D.i0*GG+H.i1]
               + w10*pl[D.i1*GG+H.i0] + w11*pl[D.i1*GG+H.i1];
      const float* ll = al + (p*CAPP + c)*GG;
      float ft = pv * (ll[D.i0] + fd*(ll[D.i1] - ll[D.i0]));
      int k = p*CAPP + c;
      for (int a = 0; a < ADIM; a++) acc[a] = fmaf(ft, W[a*KTOT + k], acc[a]);
    }
  }
  outv[n] = sigma;
  for (int a = 0; a < ADIM; a++) outv[NPTS + (size_t)n*ADIM + a] = acc[a];
}

extern "C" void kernel_launch(void* const* d_in, const int* in_sizes, int n_in,
                              void* d_out, int out_size, void* d_ws, size_t ws_size,
                              hipStream_t stream){
  const float* xyz    = (const float*)d_in[0];
  const float* dplane = (const float*)d_in[1];
  const float* dline  = (const float*)d_in[2];
  const float* aplane = (const float*)d_in[3];
  const float* aline  = (const float*)d_in[4];
  const float* W      = (const float*)d_in[5];
  float* outv = (float*)d_out;

  const size_t sz_dpt  = (size_t)3*GG*GG*CDEN*2;
  const size_t sz_apt  = (size_t)3*GG*GG*CAPP*2;
  const size_t sz_dlt  = (size_t)3*GG*CDEN*2;
  const size_t sz_alt  = (size_t)3*GG*CAPP*2;
  const size_t sz_bfr  = (size_t)3*2*2*64*16;
  const size_t sz_hist = (size_t)NBUCK*4;
  const size_t sz_offs = (size_t)NBUCK*4;
  const size_t sz_keys = (size_t)NPTS*2;
  const size_t sz_xyzq = (size_t)NPTS*16;

  const size_t off_apt  = sz_dpt;
  const size_t off_dlt  = off_apt + sz_apt;
  const size_t off_alt  = off_dlt + sz_dlt;
  const size_t off_bfr  = off_alt + sz_alt;
  const size_t off_hist = off_bfr + sz_bfr;
  const size_t off_offs = off_hist + sz_hist;
  const size_t off_keys = off_offs + sz_offs;
  const size_t off_xyzq = off_keys + sz_keys;
  const size_t need_tab  = off_hist;
  const size_t need_full = off_xyzq + sz_xyzq;

  if (ws_size < need_tab){
    sample_naive<<<(NPTS+255)/256, 256, 0, stream>>>(xyz, dplane, dline, aplane, aline, W, outv);
    return;
  }

  u16*   dpt = (u16*)((char*)d_ws);
  u16*   apt = (u16*)((char*)d_ws + off_apt);
  u16*   dlt = (u16*)((char*)d_ws + off_dlt);
  u16*   alt = (u16*)((char*)d_ws + off_alt);
  uint4* bfr = (uint4*)((char*)d_ws + off_bfr);

  if (ws_size < need_full){
    prep_all<<<2*TPBLK + 7, 256, 0, stream>>>(dplane, aplane, dline, aline, W, xyz,
                                              dpt, apt, dlt, alt, bfr, nullptr, nullptr);
    sample_mfma<false><<<NBLK64, 64, 0, stream>>>(nullptr, xyz, dpt, apt, dlt, alt, bfr, outv);
    return;
  }

  u32*    hist = (u32*)((char*)d_ws + off_hist);
  u32*    offs = (u32*)((char*)d_ws + off_offs);
  u16*    keys = (u16*)((char*)d_ws + off_keys);
  float4* xyzq = (float4*)((char*)d_ws + off_xyzq);

  hipMemsetAsync(hist, 0, sz_hist, stream);
  prep_all<<<2*TPBLK + 7 + NBLK, 256, 0, stream>>>(dplane, aplane, dline, aline, W, xyz,
                                                   dpt, apt, dlt, alt, bfr, hist, keys);
  scan_hist<<<1, 1024, 0, stream>>>(hist, offs);
  scatter_pts<<<NBLK, 256, 0, stream>>>(xyz, keys, offs, xyzq);
  sample_mfma<true><<<NBLK64, 64, 0, stream>>>(xyzq, nullptr, dpt, apt, dlt, alt, bfr, outv);
}

// Round 10
// 247.771 us; speedup vs baseline: 1.0738x; 1.0259x over previous
//
#include <hip/hip_runtime.h>

#define GG    300
#define NPTS  524288
#define CDEN  16
#define CAPP  48
#define ADIM  27
#define KTOT  144
#define TK    72      // LDS A row stride in bf16: cols 0..47 data, 48..63 zero, 64..71 pad
#define NBUCK 32768   // 15-bit Morton buckets
#define NBLK  (NPTS/256)
#define NBLK64 (NPTS/64)
#define CHUNK64 (NBLK64/8)
#define TPBLK ((3*GG*GG + 255)/256)   // 1055

typedef unsigned int u32;
typedef unsigned short u16;
typedef __attribute__((ext_vector_type(8))) short s16x8;
typedef __attribute__((ext_vector_type(4))) float f32x4;

__device__ __forceinline__ u16 f2bf(float f){
  u32 u = __float_as_uint(f);
  u32 r = u + 0x7FFFu + ((u >> 16) & 1u);   // RNE
  return (u16)(r >> 16);
}
__device__ __forceinline__ float bflo(u32 u){ return __uint_as_float(u << 16); }
__device__ __forceinline__ float bfhi(u32 u){ return __uint_as_float(u & 0xFFFF0000u); }

struct IdxW { int i0, i1; float f; };
__device__ __forceinline__ IdxW idxw(float c){
  float x  = (c + 1.0f) * 0.5f * (float)(GG - 1);
  float x0 = floorf(x);
  IdxW r;
  r.f = x - x0;
  int i0 = (int)x0;
  i0 = i0 < 0 ? 0 : (i0 > GG-1 ? GG-1 : i0);
  int i1 = i0 + 1; if (i1 > GG-1) i1 = GG-1;
  r.i0 = i0; r.i1 = i1;
  return r;
}
__device__ __forceinline__ int cell_of(float c){
  float x = (c + 1.0f) * 0.5f * (float)(GG - 1);
  int i = (int)floorf(x);
  return i < 0 ? 0 : (i > GG-1 ? GG-1 : i);
}
__device__ __forceinline__ u32 spread5(u32 v){
  v &= 0x1F;
  v = (v | (v << 8)) & 0x100F;
  v = (v | (v << 4)) & 0x10C3;
  v = (v | (v << 2)) & 0x1249;
  return v;
}

// sample 8 channels: bilinear plane * linear line -> ft[0..7]
__device__ __forceinline__ void sample8(const u16* P00, const u16* P01,
    const u16* P10, const u16* P11, const u16* L0, const u16* L1,
    float w00, float w01, float w10, float w11, float fd, float* ft)
{
  uint4 u00 = *(const uint4*)P00;
  uint4 u01 = *(const uint4*)P01;
  uint4 u10 = *(const uint4*)P10;
  uint4 u11 = *(const uint4*)P11;
  uint4 ul0 = *(const uint4*)L0;
  uint4 ul1 = *(const uint4*)L1;
  u32 a00[4]={u00.x,u00.y,u00.z,u00.w};
  u32 a01[4]={u01.x,u01.y,u01.z,u01.w};
  u32 a10[4]={u10.x,u10.y,u10.z,u10.w};
  u32 a11[4]={u11.x,u11.y,u11.z,u11.w};
  u32 al0[4]={ul0.x,ul0.y,ul0.z,ul0.w};
  u32 al1[4]={ul1.x,ul1.y,ul1.z,ul1.w};
  #pragma unroll
  for (int i = 0; i < 4; i++){
    float plo = w00*bflo(a00[i]) + w01*bflo(a01[i]) + w10*bflo(a10[i]) + w11*bflo(a11[i]);
    float phi = w00*bfhi(a00[i]) + w01*bfhi(a01[i]) + w10*bfhi(a10[i]) + w11*bfhi(a11[i]);
    float l0l = bflo(al0[i]), l1l = bflo(al1[i]);
    float l0h = bfhi(al0[i]), l1h = bfhi(al1[i]);
    ft[2*i+0] = plo * (l0l + fd*(l1l - l0l));
    ft[2*i+1] = phi * (l0h + fd*(l1h - l0h));
  }
}

// ---- fused prep: LDS-staged transposes + lines + B-frags + Morton hist/keys ----
__global__ __launch_bounds__(256) void prep_all(
    const float* __restrict__ dplane, const float* __restrict__ aplane,
    const float* __restrict__ dline,  const float* __restrict__ aline,
    const float* __restrict__ W,      const float* __restrict__ xyz,
    u16* __restrict__ dpt, u16* __restrict__ apt,
    u16* __restrict__ dlt, u16* __restrict__ alt,
    uint4* __restrict__ Bfr, u32* __restrict__ hist, u16* __restrict__ keys)
{
  __shared__ __align__(16) u16 T[256*52];   // 26.6 KB staging
  const int b = blockIdx.x;
  const int tid = threadIdx.x;
  if (b < TPBLK){
    // density plane transpose [3][16][G*G] -> [cell][16]
    const int cell0 = b*256;
    const int ncell = min(256, 3*GG*GG - cell0);
    const int cell  = cell0 + tid;
    if (tid < ncell){
      int p = cell/(GG*GG), rem = cell - p*(GG*GG);
      #pragma unroll
      for (int c = 0; c < CDEN; c++)
        T[tid*20 + c] = f2bf(dplane[((size_t)(p*CDEN+c))*(GG*GG) + rem]);
    }
    __syncthreads();
    uint2* dst = (uint2*)(dpt + (size_t)cell0*CDEN);
    const int nch = ncell*4;                 // 8B chunks (32B/cell)
    #pragma unroll
    for (int k = 0; k < 4; k++){
      int idx = k*256 + tid;
      if (idx < nch){
        int cl = idx >> 2, j = idx & 3;
        dst[idx] = *(const uint2*)(T + cl*20 + j*4);
      }
    }
  } else if (b < 2*TPBLK){
    // app plane transpose [3][48][G*G] -> [cell][48]
    const int cell0 = (b - TPBLK)*256;
    const int ncell = min(256, 3*GG*GG - cell0);
    const int cell  = cell0 + tid;
    if (tid < ncell){
      int p = cell/(GG*GG), rem = cell - p*(GG*GG);
      #pragma unroll
      for (int c = 0; c < CAPP; c++)
        T[tid*52 + c] = f2bf(aplane[((size_t)(p*CAPP+c))*(GG*GG) + rem]);
    }
    __syncthreads();
    uint2* dst = (uint2*)(apt + (size_t)cell0*CAPP);
    const int nch = ncell*12;                // 8B chunks (96B/cell)
    #pragma unroll
    for (int k = 0; k < 12; k++){
      int idx = k*256 + tid;
      if (idx < nch){
        int cl = idx/12, j = idx - cl*12;
        dst[idx] = *(const uint2*)(T + cl*52 + j*4);
      }
    }
  } else if (b < 2*TPBLK + 4){
    int t = (b - 2*TPBLK)*256 + tid;
    if (t < 3*GG){
      int p = t / GG, d = t - p*GG;
      #pragma unroll
      for (int c = 0; c < CDEN; c++) dlt[t*CDEN + c] = f2bf(dline[(p*CDEN + c)*GG + d]);
      #pragma unroll
      for (int c = 0; c < CAPP; c++) alt[t*CAPP + c] = f2bf(aline[(p*CAPP + c)*GG + d]);
    }
  } else if (b < 2*TPBLK + 7){
    int t = (b - (2*TPBLK + 4))*256 + tid;
    if (t < 3*2*2*64){
      int lane = t & 63;
      int st = (t >> 6) & 1;
      int nt = (t >> 7) & 1;
      int p  = t >> 8;
      int a  = nt*16 + (lane & 15);
      int kb = st*32 + ((lane >> 4) * 8);
      u32 d[4];
      #pragma unroll
      for (int j2 = 0; j2 < 4; j2++){
        int k0 = kb + 2*j2, k1 = k0 + 1;
        u32 lo = (a < ADIM && k0 < 48) ? (u32)f2bf(W[a*KTOT + p*48 + k0]) : 0u;
        u32 hi = (a < ADIM && k1 < 48) ? (u32)f2bf(W[a*KTOT + p*48 + k1]) : 0u;
        d[j2] = lo | (hi << 16);
      }
      Bfr[t] = make_uint4(d[0], d[1], d[2], d[3]);
    }
  } else {
    int n = (b - (2*TPBLK + 7))*256 + tid;
    float X = xyz[3*n+0], Y = xyz[3*n+1], Z = xyz[3*n+2];
    u32 bx = (u32)(cell_of(X) >> 4);
    u32 by = (u32)(cell_of(Y) >> 4);
    u32 bz = (u32)(cell_of(Z) >> 4);
    u32 key = spread5(bx) | (spread5(by) << 1) | (spread5(bz) << 2);
    keys[n] = (u16)key;
    atomicAdd(&hist[key], 1u);
  }
}

// ---- 2-level scan: scan1 = per-1024-chunk exclusive scan (coalesced, 32 blocks),
// scan2 = scan of 32 chunk sums. Old single-block scan was ~27us: 64K
// uncoalesced lane-addresses on ONE CU. ----
__global__ __launch_bounds__(1024) void scan1(const u32* __restrict__ hist,
                                              u32* __restrict__ offs,
                                              u32* __restrict__ csum){
  __shared__ u32 part[1024];
  const int t = threadIdx.x;
  const int i = blockIdx.x*1024 + t;
  u32 v = hist[i];
  part[t] = v;
  __syncthreads();
  for (int off = 1; off < 1024; off <<= 1){
    u32 x = (t >= off) ? part[t - off] : 0;
    __syncthreads();
    part[t] += x;
    __syncthreads();
  }
  offs[i] = part[t] - v;               // chunk-local exclusive prefix
  if (t == 1023) csum[blockIdx.x] = part[t];
}

__global__ __launch_bounds__(64) void scan2(const u32* __restrict__ csum,
                                            u32* __restrict__ cbase){
  if (threadIdx.x == 0){
    u32 s = 0;
    for (int i = 0; i < NBUCK/1024; i++){ cbase[i] = s; s += csum[i]; }
  }
}

// scatter: pos = chunk base + chunk-local prefix; pack {x,y,z,orig_idx}
__global__ __launch_bounds__(256) void scatter_pts(const float* __restrict__ xyz,
                                                   const u16* __restrict__ keys,
                                                   u32* __restrict__ offs,
                                                   const u32* __restrict__ cbase,
                                                   float4* __restrict__ xyzq){
  int n = blockIdx.x*256 + threadIdx.x;
  u32 key = keys[n];
  u32 pos = cbase[key >> 10] + atomicAdd(&offs[key], 1u);
  float4 q;
  q.x = xyz[3*n+0]; q.y = xyz[3*n+1]; q.z = xyz[3*n+2];
  q.w = __int_as_float(n);
  xyzq[pos] = q;
}

// ---- main: fused sampling + per-wave MFMA GEMM. ONE WAVE PER BLOCK ----
// R6-proven config: plain __launch_bounds__(64). DO NOT add the 2nd
// launch_bounds arg on this hipcc: (256,4) forced 64 VGPR + 400MB spill (R4);
// (64,5) silently miscomputed (R8, absmax 1.6e-2). Kernel is at its
// address-throughput roofline: 144 gather instrs/point = 295K lane-addrs/CU
// @ ~1 addr/cy = 123us model vs ~133 measured. Only cross-lane dedupe beats it.
template<bool SORTED>
__global__ __launch_bounds__(64) void sample_mfma(
    const float4* __restrict__ xyzq,  // sorted {x,y,z,idx} (SORTED)
    const float* __restrict__ xyz,    // original (fallback)
    const u16*  __restrict__ dpt,     // [3][G][G][16]
    const u16*  __restrict__ apt,     // [3][G][G][48]
    const u16*  __restrict__ dlt,     // [3][G][16]
    const u16*  __restrict__ alt,     // [3][G][48]
    const uint4* __restrict__ Bfr,    // [3][2][2][64]
    float* __restrict__ outv)         // [N] sigma ++ [N][27] app
{
  __shared__ __align__(16) u16 Asm[64*TK];   // 9216 B, wave-private
  const int lane = threadIdx.x;
  int bid = blockIdx.x;
  if (SORTED) bid = (bid & 7)*CHUNK64 + (bid >> 3);   // XCD-chunked Morton octants
  const int n = bid*64 + lane;

  float X, Y, Z; int pn;
  if (SORTED){
    float4 q = xyzq[n];
    X = q.x; Y = q.y; Z = q.z; pn = __float_as_int(q.w);
  } else {
    X = xyz[3*n+0]; Y = xyz[3*n+1]; Z = xyz[3*n+2]; pn = n;
  }

  u16* Arow = Asm + lane*TK;
  const u16* Awave = Asm;

  float sigma = 0.f;
  f32x4 acc[4][2];
  #pragma unroll
  for (int t = 0; t < 4; t++){
    acc[t][0] = (f32x4){0.f,0.f,0.f,0.f};
    acc[t][1] = (f32x4){0.f,0.f,0.f,0.f};
  }

  uint4 z4 = make_uint4(0,0,0,0);
  *(uint4*)(Arow + 48) = z4;
  *(uint4*)(Arow + 56) = z4;

  #pragma unroll 1
  for (int p = 0; p < 3; p++){
    const float dc = (p==0) ? Z : ((p==1) ? Y : X);
    const float hc = (p==0) ? Y : Z;

    uint4 b00 = Bfr[(p*4 + 0)*64 + lane];
    uint4 b01 = Bfr[(p*4 + 1)*64 + lane];
    uint4 b10 = Bfr[(p*4 + 2)*64 + lane];
    uint4 b11 = Bfr[(p*4 + 3)*64 + lane];

    IdxW D = idxw(dc), H = idxw(hc);
    const float fd = D.f, fh = H.f;
    const float w00 = (1.f-fd)*(1.f-fh), w01 = (1.f-fd)*fh;
    const float w10 = fd*(1.f-fh),       w11 = fd*fh;

    { // density -> sigma
      const u16* P00 = dpt + ((p*GG+D.i0)*GG+H.i0)*CDEN;
      const u16* P01 = dpt + ((p*GG+D.i0)*GG+H.i1)*CDEN;
      const u16* P10 = dpt + ((p*GG+D.i1)*GG+H.i0)*CDEN;
      const u16* P11 = dpt + ((p*GG+D.i1)*GG+H.i1)*CDEN;
      const u16* L0  = dlt + (p*GG+D.i0)*CDEN;
      const u16* L1  = dlt + (p*GG+D.i1)*CDEN;
      #pragma unroll
      for (int g = 0; g < 2; g++){
        float ft[8];
        sample8(P00+g*8, P01+g*8, P10+g*8, P11+g*8, L0+g*8, L1+g*8,
                w00,w01,w10,w11, fd, ft);
        sigma += ((ft[0]+ft[1])+(ft[2]+ft[3])) + ((ft[4]+ft[5])+(ft[6]+ft[7]));
      }
    }

    { // app feats -> LDS A tile (unroll 2: bounded live ranges, no spill)
      const u16* P00 = apt + ((p*GG+D.i0)*GG+H.i0)*CAPP;
      const u16* P01 = apt + ((p*GG+D.i0)*GG+H.i1)*CAPP;
      const u16* P10 = apt + ((p*GG+D.i1)*GG+H.i0)*CAPP;
      const u16* P11 = apt + ((p*GG+D.i1)*GG+H.i1)*CAPP;
      const u16* L0  = alt + (p*GG+D.i0)*CAPP;
      const u16* L1  = alt + (p*GG+D.i1)*CAPP;
      #pragma unroll 2
      for (int g = 0; g < 6; g++){
        float ft[8];
        sample8(P00+g*8, P01+g*8, P10+g*8, P11+g*8, L0+g*8, L1+g*8,
                w00,w01,w10,w11, fd, ft);
        uint4 d;
        d.x = (u32)f2bf(ft[0]) | ((u32)f2bf(ft[1]) << 16);
        d.y = (u32)f2bf(ft[2]) | ((u32)f2bf(ft[3]) << 16);
        d.z = (u32)f2bf(ft[4]) | ((u32)f2bf(ft[5]) << 16);
        d.w = (u32)f2bf(ft[6]) | ((u32)f2bf(ft[7]) << 16);
        *(uint4*)(Arow + g*8) = d;
      }
    }

    // compiler-only fence: LDS ops within a wave complete in order in HW.
    asm volatile("" ::: "memory");

    #pragma unroll
    for (int t = 0; t < 4; t++){
      const u16* ab = Awave + (t*16 + (lane & 15))*TK + ((lane >> 4) * 8);
      s16x8 a0 = __builtin_bit_cast(s16x8, *(const uint4*)ab);
      s16x8 a1 = __builtin_bit_cast(s16x8, *(const uint4*)(ab + 32));
      acc[t][0] = __builtin_amdgcn_mfma_f32_16x16x32_bf16(a0, __builtin_bit_cast(s16x8,b00), acc[t][0], 0,0,0);
      acc[t][0] = __builtin_amdgcn_mfma_f32_16x16x32_bf16(a1, __builtin_bit_cast(s16x8,b01), acc[t][0], 0,0,0);
      acc[t][1] = __builtin_amdgcn_mfma_f32_16x16x32_bf16(a0, __builtin_bit_cast(s16x8,b10), acc[t][1], 0,0,0);
      acc[t][1] = __builtin_amdgcn_mfma_f32_16x16x32_bf16(a1, __builtin_bit_cast(s16x8,b11), acc[t][1], 0,0,0);
    }
    asm volatile("" ::: "memory");   // keep next plane's LDS writes below these reads
  }

  outv[pn] = sigma;

  float* ao = outv + NPTS;
  #pragma unroll
  for (int t = 0; t < 4; t++){
    #pragma unroll
    for (int nt = 0; nt < 2; nt++){
      int a = nt*16 + (lane & 15);
      #pragma unroll
      for (int r = 0; r < 4; r++){
        int src = t*16 + (lane >> 4)*4 + r;   // point index within wave
        int pr = __shfl(pn, src);
        if (a < ADIM)
          ao[(size_t)pr*ADIM + a] = acc[t][nt][r];
      }
    }
  }
}

// ---- fallback: direct fp32 sampling ----
__global__ void sample_naive(const float* __restrict__ xyz,
    const float* __restrict__ dp, const float* __restrict__ dl,
    const float* __restrict__ ap, const float* __restrict__ al,
    const float* __restrict__ W,  float* __restrict__ outv)
{
  int n = blockIdx.x*blockDim.x + threadIdx.x;
  if (n >= NPTS) return;
  float X = xyz[3*n], Y = xyz[3*n+1], Z = xyz[3*n+2];
  float dco[3] = {Z, Y, X};
  float hco[3] = {Y, Z, Z};
  float sigma = 0.f, acc[ADIM];
  for (int a = 0; a < ADIM; a++) acc[a] = 0.f;
  for (int p = 0; p < 3; p++){
    IdxW D = idxw(dco[p]), H = idxw(hco[p]);
    float fd = D.f, fh = H.f;
    float w00=(1.f-fd)*(1.f-fh), w01=(1.f-fd)*fh, w10=fd*(1.f-fh), w11=fd*fh;
    for (int c = 0; c < CDEN; c++){
      const float* pl = dp + (size_t)(p*CDEN + c)*GG*GG;
      float pv = w00*pl[D.i0*GG+H.i0] + w01*pl[D.i0*GG+H.i1]
               + w10*pl[D.i1*GG+H.i0] + w11*pl[D.i1*GG+H.i1];
      const float* ll = dl + (p*CDEN + c)*GG;
      sigma += pv * (ll[D.i0] + fd*(ll[D.i1] - ll[D.i0]));
    }
    for (int c = 0; c < CAPP; c++){
      const float* pl = ap + (size_t)(p*CAPP + c)*GG*GG;
      float pv = w00*pl[D.i0*GG+H.i0] + w01*pl[D.i0*GG+H.i1]
               + w10*pl[D.i1*GG+H.i0] + w11*pl[D.i1*GG+H.i1];
      const float* ll = al + (p*CAPP + c)*GG;
      float ft = pv * (ll[D.i0] + fd*(ll[D.i1] - ll[D.i0]));
      int k = p*CAPP + c;
      for (int a = 0; a < ADIM; a++) acc[a] = fmaf(ft, W[a*KTOT + k], acc[a]);
    }
  }
  outv[n] = sigma;
  for (int a = 0; a < ADIM; a++) outv[NPTS + (size_t)n*ADIM + a] = acc[a];
}

extern "C" void kernel_launch(void* const* d_in, const int* in_sizes, int n_in,
                              void* d_out, int out_size, void* d_ws, size_t ws_size,
                              hipStream_t stream){
  const float* xyz    = (const float*)d_in[0];
  const float* dplane = (const float*)d_in[1];
  const float* dline  = (const float*)d_in[2];
  const float* aplane = (const float*)d_in[3];
  const float* aline  = (const float*)d_in[4];
  const float* W      = (const float*)d_in[5];
  float* outv = (float*)d_out;

  const size_t sz_dpt  = (size_t)3*GG*GG*CDEN*2;
  const size_t sz_apt  = (size_t)3*GG*GG*CAPP*2;
  const size_t sz_dlt  = (size_t)3*GG*CDEN*2;
  const size_t sz_alt  = (size_t)3*GG*CAPP*2;
  const size_t sz_bfr  = (size_t)3*2*2*64*16;
  const size_t sz_hist = (size_t)NBUCK*4;
  const size_t sz_offs = (size_t)NBUCK*4;
  const size_t sz_csum = (size_t)(NBUCK/1024)*4;
  const size_t sz_cbase= (size_t)(NBUCK/1024)*4;
  const size_t sz_keys = (size_t)NPTS*2;
  const size_t sz_xyzq = (size_t)NPTS*16;

  const size_t off_apt  = sz_dpt;
  const size_t off_dlt  = off_apt + sz_apt;
  const size_t off_alt  = off_dlt + sz_dlt;
  const size_t off_bfr  = off_alt + sz_alt;
  const size_t off_hist = off_bfr + sz_bfr;
  const size_t off_offs = off_hist + sz_hist;
  const size_t off_csum = off_offs + sz_offs;
  const size_t off_cbase= off_csum + sz_csum;
  const size_t off_keys = off_cbase + sz_cbase;
  const size_t off_xyzq = off_keys + sz_keys;
  const size_t need_tab  = off_hist;
  const size_t need_full = off_xyzq + sz_xyzq;

  if (ws_size < need_tab){
    sample_naive<<<(NPTS+255)/256, 256, 0, stream>>>(xyz, dplane, dline, aplane, aline, W, outv);
    return;
  }

  u16*   dpt = (u16*)((char*)d_ws);
  u16*   apt = (u16*)((char*)d_ws + off_apt);
  u16*   dlt = (u16*)((char*)d_ws + off_dlt);
  u16*   alt = (u16*)((char*)d_ws + off_alt);
  uint4* bfr = (uint4*)((char*)d_ws + off_bfr);

  if (ws_size < need_full){
    prep_all<<<2*TPBLK + 7, 256, 0, stream>>>(dplane, aplane, dline, aline, W, xyz,
                                              dpt, apt, dlt, alt, bfr, nullptr, nullptr);
    sample_mfma<false><<<NBLK64, 64, 0, stream>>>(nullptr, xyz, dpt, apt, dlt, alt, bfr, outv);
    return;
  }

  u32*    hist = (u32*)((char*)d_ws + off_hist);
  u32*    offs = (u32*)((char*)d_ws + off_offs);
  u32*    csum = (u32*)((char*)d_ws + off_csum);
  u32*    cbase= (u32*)((char*)d_ws + off_cbase);
  u16*    keys = (u16*)((char*)d_ws + off_keys);
  float4* xyzq = (float4*)((char*)d_ws + off_xyzq);

  hipMemsetAsync(hist, 0, sz_hist, stream);
  prep_all<<<2*TPBLK + 7 + NBLK, 256, 0, stream>>>(dplane, aplane, dline, aline, W, xyz,
                                                   dpt, apt, dlt, alt, bfr, hist, keys);
  scan1<<<NBUCK/1024, 1024, 0, stream>>>(hist, offs, csum);
  scan2<<<1, 64, 0, stream>>>(csum, cbase);
  scatter_pts<<<NBLK, 256, 0, stream>>>(xyz, keys, offs, cbase, xyzq);
  sample_mfma<true><<<NBLK64, 64, 0, stream>>>(xyzq, nullptr, dpt, apt, dlt, alt, bfr, outv);
}

// Round 11
// 202.013 us; speedup vs baseline: 1.3170x; 1.2265x over previous
//
#include <hip/hip_runtime.h>

#define GG    300
#define NPTS  524288
#define CDEN  16
#define CAPP  48
#define ADIM  27
#define KTOT  144
#define TK    72      // LDS A row stride in bf16: cols 0..47 data, 48..63 zero, 64..71 pad
#define NBUCK (300*512)      // (ycell<<9)|zcell buckets = 153600 = 150*1024
#define NCHUNK (NBUCK/1024)  // 150
#define NBLK  (NPTS/256)
#define NBLK64 (NPTS/64)
#define CHUNK64 (NBLK64/8)
#define TPBLK ((3*GG*GG + 255)/256)   // 1055

typedef unsigned int u32;
typedef unsigned short u16;
typedef __attribute__((ext_vector_type(8))) short s16x8;
typedef __attribute__((ext_vector_type(4))) float f32x4;

__device__ __forceinline__ u16 f2bf(float f){
  u32 u = __float_as_uint(f);
  u32 r = u + 0x7FFFu + ((u >> 16) & 1u);   // RNE
  return (u16)(r >> 16);
}
__device__ __forceinline__ float bflo(u32 u){ return __uint_as_float(u << 16); }
__device__ __forceinline__ float bfhi(u32 u){ return __uint_as_float(u & 0xFFFF0000u); }

struct IdxW { int i0, i1; float f; };
__device__ __forceinline__ IdxW idxw(float c){
  float x  = (c + 1.0f) * 0.5f * (float)(GG - 1);
  float x0 = floorf(x);
  IdxW r;
  r.f = x - x0;
  int i0 = (int)x0;
  i0 = i0 < 0 ? 0 : (i0 > GG-1 ? GG-1 : i0);
  int i1 = i0 + 1; if (i1 > GG-1) i1 = GG-1;
  r.i0 = i0; r.i1 = i1;
  return r;
}
__device__ __forceinline__ int cell_of(float c){
  float x = (c + 1.0f) * 0.5f * (float)(GG - 1);
  int i = (int)floorf(x);
  return i < 0 ? 0 : (i > GG-1 ? GG-1 : i);
}

// sample 8 channels: bilinear plane * linear line -> ft[0..7]
__device__ __forceinline__ void sample8(const u16* P00, const u16* P01,
    const u16* P10, const u16* P11, const u16* L0, const u16* L1,
    float w00, float w01, float w10, float w11, float fd, float* ft)
{
  uint4 u00 = *(const uint4*)P00;
  uint4 u01 = *(const uint4*)P01;
  uint4 u10 = *(const uint4*)P10;
  uint4 u11 = *(const uint4*)P11;
  uint4 ul0 = *(const uint4*)L0;
  uint4 ul1 = *(const uint4*)L1;
  u32 a00[4]={u00.x,u00.y,u00.z,u00.w};
  u32 a01[4]={u01.x,u01.y,u01.z,u01.w};
  u32 a10[4]={u10.x,u10.y,u10.z,u10.w};
  u32 a11[4]={u11.x,u11.y,u11.z,u11.w};
  u32 al0[4]={ul0.x,ul0.y,ul0.z,ul0.w};
  u32 al1[4]={ul1.x,ul1.y,ul1.z,ul1.w};
  #pragma unroll
  for (int i = 0; i < 4; i++){
    float plo = w00*bflo(a00[i]) + w01*bflo(a01[i]) + w10*bflo(a10[i]) + w11*bflo(a11[i]);
    float phi = w00*bfhi(a00[i]) + w01*bfhi(a01[i]) + w10*bfhi(a10[i]) + w11*bfhi(a11[i]);
    float l0l = bflo(al0[i]), l1l = bflo(al1[i]);
    float l0h = bfhi(al0[i]), l1h = bfhi(al1[i]);
    ft[2*i+0] = plo * (l0l + fd*(l1l - l0l));
    ft[2*i+1] = phi * (l0h + fd*(l1h - l0h));
  }
}

// ---- fused prep: LDS-staged transposes + lines + B-frags + (Y,Z)-key hist ----
// Sort key = ycell*512 + zcell (full resolution). All ~5.8 residents of a
// (Y,Z) plane cell become CONSECUTIVE in sorted order -> a 64-pt wave spans
// ~11 distinct cells for planes 0 (Z,Y) and 1 (Y,Z) -> their corner/line
// gathers have ~11 unique addresses across 64 lanes. Experiment: is the TA
// cost per-lane-address (flat) or per-unique-address (sample ~-40%)?
__global__ __launch_bounds__(256) void prep_all(
    const float* __restrict__ dplane, const float* __restrict__ aplane,
    const float* __restrict__ dline,  const float* __restrict__ aline,
    const float* __restrict__ W,      const float* __restrict__ xyz,
    u16* __restrict__ dpt, u16* __restrict__ apt,
    u16* __restrict__ dlt, u16* __restrict__ alt,
    uint4* __restrict__ Bfr, u32* __restrict__ hist, u32* __restrict__ keys)
{
  __shared__ __align__(16) u16 T[256*52];   // 26.6 KB staging
  const int b = blockIdx.x;
  const int tid = threadIdx.x;
  if (b < TPBLK){
    // density plane transpose [3][16][G*G] -> [cell][16]
    const int cell0 = b*256;
    const int ncell = min(256, 3*GG*GG - cell0);
    const int cell  = cell0 + tid;
    if (tid < ncell){
      int p = cell/(GG*GG), rem = cell - p*(GG*GG);
      #pragma unroll
      for (int c = 0; c < CDEN; c++)
        T[tid*20 + c] = f2bf(dplane[((size_t)(p*CDEN+c))*(GG*GG) + rem]);
    }
    __syncthreads();
    uint2* dst = (uint2*)(dpt + (size_t)cell0*CDEN);
    const int nch = ncell*4;                 // 8B chunks (32B/cell)
    #pragma unroll
    for (int k = 0; k < 4; k++){
      int idx = k*256 + tid;
      if (idx < nch){
        int cl = idx >> 2, j = idx & 3;
        dst[idx] = *(const uint2*)(T + cl*20 + j*4);
      }
    }
  } else if (b < 2*TPBLK){
    // app plane transpose [3][48][G*G] -> [cell][48]
    const int cell0 = (b - TPBLK)*256;
    const int ncell = min(256, 3*GG*GG - cell0);
    const int cell  = cell0 + tid;
    if (tid < ncell){
      int p = cell/(GG*GG), rem = cell - p*(GG*GG);
      #pragma unroll
      for (int c = 0; c < CAPP; c++)
        T[tid*52 + c] = f2bf(aplane[((size_t)(p*CAPP+c))*(GG*GG) + rem]);
    }
    __syncthreads();
    uint2* dst = (uint2*)(apt + (size_t)cell0*CAPP);
    const int nch = ncell*12;                // 8B chunks (96B/cell)
    #pragma unroll
    for (int k = 0; k < 12; k++){
      int idx = k*256 + tid;
      if (idx < nch){
        int cl = idx/12, j = idx - cl*12;
        dst[idx] = *(const uint2*)(T + cl*52 + j*4);
      }
    }
  } else if (b < 2*TPBLK + 4){
    int t = (b - 2*TPBLK)*256 + tid;
    if (t < 3*GG){
      int p = t / GG, d = t - p*GG;
      #pragma unroll
      for (int c = 0; c < CDEN; c++) dlt[t*CDEN + c] = f2bf(dline[(p*CDEN + c)*GG + d]);
      #pragma unroll
      for (int c = 0; c < CAPP; c++) alt[t*CAPP + c] = f2bf(aline[(p*CAPP + c)*GG + d]);
    }
  } else if (b < 2*TPBLK + 7){
    int t = (b - (2*TPBLK + 4))*256 + tid;
    if (t < 3*2*2*64){
      int lane = t & 63;
      int st = (t >> 6) & 1;
      int nt = (t >> 7) & 1;
      int p  = t >> 8;
      int a  = nt*16 + (lane & 15);
      int kb = st*32 + ((lane >> 4) * 8);
      u32 d[4];
      #pragma unroll
      for (int j2 = 0; j2 < 4; j2++){
        int k0 = kb + 2*j2, k1 = k0 + 1;
        u32 lo = (a < ADIM && k0 < 48) ? (u32)f2bf(W[a*KTOT + p*48 + k0]) : 0u;
        u32 hi = (a < ADIM && k1 < 48) ? (u32)f2bf(W[a*KTOT + p*48 + k1]) : 0u;
        d[j2] = lo | (hi << 16);
      }
      Bfr[t] = make_uint4(d[0], d[1], d[2], d[3]);
    }
  } else {
    int n = (b - (2*TPBLK + 7))*256 + tid;
    float Y = xyz[3*n+1], Z = xyz[3*n+2];
    u32 key = ((u32)cell_of(Y) << 9) | (u32)cell_of(Z);
    keys[n] = key;
    atomicAdd(&hist[key], 1u);
  }
}

// ---- 2-level scan over 153600 buckets ----
__global__ __launch_bounds__(1024) void scan1(const u32* __restrict__ hist,
                                              u32* __restrict__ offs,
                                              u32* __restrict__ csum){
  __shared__ u32 part[1024];
  const int t = threadIdx.x;
  const int i = blockIdx.x*1024 + t;
  u32 v = hist[i];
  part[t] = v;
  __syncthreads();
  for (int off = 1; off < 1024; off <<= 1){
    u32 x = (t >= off) ? part[t - off] : 0;
    __syncthreads();
    part[t] += x;
    __syncthreads();
  }
  offs[i] = part[t] - v;               // chunk-local exclusive prefix
  if (t == 1023) csum[blockIdx.x] = part[t];
}

__global__ __launch_bounds__(256) void scan2(const u32* __restrict__ csum,
                                             u32* __restrict__ cbase){
  __shared__ u32 part[256];
  const int t = threadIdx.x;
  u32 v = (t < NCHUNK) ? csum[t] : 0;
  part[t] = v;
  __syncthreads();
  for (int off = 1; off < 256; off <<= 1){
    u32 x = (t >= off) ? part[t - off] : 0;
    __syncthreads();
    part[t] += x;
    __syncthreads();
  }
  if (t < NCHUNK) cbase[t] = part[t] - v;   // exclusive
}

// scatter: pos = chunk base + chunk-local prefix; pack {x,y,z,orig_idx}
__global__ __launch_bounds__(256) void scatter_pts(const float* __restrict__ xyz,
                                                   const u32* __restrict__ keys,
                                                   u32* __restrict__ offs,
                                                   const u32* __restrict__ cbase,
                                                   float4* __restrict__ xyzq){
  int n = blockIdx.x*256 + threadIdx.x;
  u32 key = keys[n];
  u32 pos = cbase[key >> 10] + atomicAdd(&offs[key], 1u);
  float4 q;
  q.x = xyz[3*n+0]; q.y = xyz[3*n+1]; q.z = xyz[3*n+2];
  q.w = __int_as_float(n);
  xyzq[pos] = q;
}

// ---- main: fused sampling + per-wave MFMA GEMM. ONE WAVE PER BLOCK ----
// R6-proven config: plain __launch_bounds__(64). DO NOT add the 2nd
// launch_bounds arg on this hipcc: (256,4) forced 64 VGPR + 400MB spill (R4);
// (64,5) silently miscomputed (R8, absmax 1.6e-2).
template<bool SORTED>
__global__ __launch_bounds__(64) void sample_mfma(
    const float4* __restrict__ xyzq,  // sorted {x,y,z,idx} (SORTED)
    const float* __restrict__ xyz,    // original (fallback)
    const u16*  __restrict__ dpt,     // [3][G][G][16]
    const u16*  __restrict__ apt,     // [3][G][G][48]
    const u16*  __restrict__ dlt,     // [3][G][16]
    const u16*  __restrict__ alt,     // [3][G][48]
    const uint4* __restrict__ Bfr,    // [3][2][2][64]
    float* __restrict__ outv)         // [N] sigma ++ [N][27] app
{
  __shared__ __align__(16) u16 Asm[64*TK];   // 9216 B, wave-private
  const int lane = threadIdx.x;
  int bid = blockIdx.x;
  if (SORTED) bid = (bid & 7)*CHUNK64 + (bid >> 3);   // XCD-chunked sorted ranges
  const int n = bid*64 + lane;

  float X, Y, Z; int pn;
  if (SORTED){
    float4 q = xyzq[n];
    X = q.x; Y = q.y; Z = q.z; pn = __float_as_int(q.w);
  } else {
    X = xyz[3*n+0]; Y = xyz[3*n+1]; Z = xyz[3*n+2]; pn = n;
  }

  u16* Arow = Asm + lane*TK;
  const u16* Awave = Asm;

  float sigma = 0.f;
  f32x4 acc[4][2];
  #pragma unroll
  for (int t = 0; t < 4; t++){
    acc[t][0] = (f32x4){0.f,0.f,0.f,0.f};
    acc[t][1] = (f32x4){0.f,0.f,0.f,0.f};
  }

  uint4 z4 = make_uint4(0,0,0,0);
  *(uint4*)(Arow + 48) = z4;
  *(uint4*)(Arow + 56) = z4;

  #pragma unroll 1
  for (int p = 0; p < 3; p++){
    const float dc = (p==0) ? Z : ((p==1) ? Y : X);
    const float hc = (p==0) ? Y : Z;

    uint4 b00 = Bfr[(p*4 + 0)*64 + lane];
    uint4 b01 = Bfr[(p*4 + 1)*64 + lane];
    uint4 b10 = Bfr[(p*4 + 2)*64 + lane];
    uint4 b11 = Bfr[(p*4 + 3)*64 + lane];

    IdxW D = idxw(dc), H = idxw(hc);
    const float fd = D.f, fh = H.f;
    const float w00 = (1.f-fd)*(1.f-fh), w01 = (1.f-fd)*fh;
    const float w10 = fd*(1.f-fh),       w11 = fd*fh;

    { // density -> sigma
      const u16* P00 = dpt + ((p*GG+D.i0)*GG+H.i0)*CDEN;
      const u16* P01 = dpt + ((p*GG+D.i0)*GG+H.i1)*CDEN;
      const u16* P10 = dpt + ((p*GG+D.i1)*GG+H.i0)*CDEN;
      const u16* P11 = dpt + ((p*GG+D.i1)*GG+H.i1)*CDEN;
      const u16* L0  = dlt + (p*GG+D.i0)*CDEN;
      const u16* L1  = dlt + (p*GG+D.i1)*CDEN;
      #pragma unroll
      for (int g = 0; g < 2; g++){
        float ft[8];
        sample8(P00+g*8, P01+g*8, P10+g*8, P11+g*8, L0+g*8, L1+g*8,
                w00,w01,w10,w11, fd, ft);
        sigma += ((ft[0]+ft[1])+(ft[2]+ft[3])) + ((ft[4]+ft[5])+(ft[6]+ft[7]));
      }
    }

    { // app feats -> LDS A tile (unroll 2: bounded live ranges, no spill)
      const u16* P00 = apt + ((p*GG+D.i0)*GG+H.i0)*CAPP;
      const u16* P01 = apt + ((p*GG+D.i0)*GG+H.i1)*CAPP;
      const u16* P10 = apt + ((p*GG+D.i1)*GG+H.i0)*CAPP;
      const u16* P11 = apt + ((p*GG+D.i1)*GG+H.i1)*CAPP;
      const u16* L0  = alt + (p*GG+D.i0)*CAPP;
      const u16* L1  = alt + (p*GG+D.i1)*CAPP;
      #pragma unroll 2
      for (int g = 0; g < 6; g++){
        float ft[8];
        sample8(P00+g*8, P01+g*8, P10+g*8, P11+g*8, L0+g*8, L1+g*8,
                w00,w01,w10,w11, fd, ft);
        uint4 d;
        d.x = (u32)f2bf(ft[0]) | ((u32)f2bf(ft[1]) << 16);
        d.y = (u32)f2bf(ft[2]) | ((u32)f2bf(ft[3]) << 16);
        d.z = (u32)f2bf(ft[4]) | ((u32)f2bf(ft[5]) << 16);
        d.w = (u32)f2bf(ft[6]) | ((u32)f2bf(ft[7]) << 16);
        *(uint4*)(Arow + g*8) = d;
      }
    }

    // compiler-only fence: LDS ops within a wave complete in order in HW.
    asm volatile("" ::: "memory");

    #pragma unroll
    for (int t = 0; t < 4; t++){
      const u16* ab = Awave + (t*16 + (lane & 15))*TK + ((lane >> 4) * 8);
      s16x8 a0 = __builtin_bit_cast(s16x8, *(const uint4*)ab);
      s16x8 a1 = __builtin_bit_cast(s16x8, *(const uint4*)(ab + 32));
      acc[t][0] = __builtin_amdgcn_mfma_f32_16x16x32_bf16(a0, __builtin_bit_cast(s16x8,b00), acc[t][0], 0,0,0);
      acc[t][0] = __builtin_amdgcn_mfma_f32_16x16x32_bf16(a1, __builtin_bit_cast(s16x8,b01), acc[t][0], 0,0,0);
      acc[t][1] = __builtin_amdgcn_mfma_f32_16x16x32_bf16(a0, __builtin_bit_cast(s16x8,b10), acc[t][1], 0,0,0);
      acc[t][1] = __builtin_amdgcn_mfma_f32_16x16x32_bf16(a1, __builtin_bit_cast(s16x8,b11), acc[t][1], 0,0,0);
    }
    asm volatile("" ::: "memory");   // keep next plane's LDS writes below these reads
  }

  outv[pn] = sigma;

  float* ao = outv + NPTS;
  #pragma unroll
  for (int t = 0; t < 4; t++){
    #pragma unroll
    for (int nt = 0; nt < 2; nt++){
      int a = nt*16 + (lane & 15);
      #pragma unroll
      for (int r = 0; r < 4; r++){
        int src = t*16 + (lane >> 4)*4 + r;   // point index within wave
        int pr = __shfl(pn, src);
        if (a < ADIM)
          ao[(size_t)pr*ADIM + a] = acc[t][nt][r];
      }
    }
  }
}

// ---- fallback: direct fp32 sampling ----
__global__ void sample_naive(const float* __restrict__ xyz,
    const float* __restrict__ dp, const float* __restrict__ dl,
    const float* __restrict__ ap, const float* __restrict__ al,
    const float* __restrict__ W,  float* __restrict__ outv)
{
  int n = blockIdx.x*blockDim.x + threadIdx.x;
  if (n >= NPTS) return;
  float X = xyz[3*n], Y = xyz[3*n+1], Z = xyz[3*n+2];
  float dco[3] = {Z, Y, X};
  float hco[3] = {Y, Z, Z};
  float sigma = 0.f, acc[ADIM];
  for (int a = 0; a < ADIM; a++) acc[a] = 0.f;
  for (int p = 0; p < 3; p++){
    IdxW D = idxw(dco[p]), H = idxw(hco[p]);
    float fd = D.f, fh = H.f;
    float w00=(1.f-fd)*(1.f-fh), w01=(1.f-fd)*fh, w10=fd*(1.f-fh), w11=fd*fh;
    for (int c = 0; c < CDEN; c++){
      const float* pl = dp + (size_t)(p*CDEN + c)*GG*GG;
      float pv = w00*pl[D.i0*GG+H.i0] + w01*pl[D.i0*GG+H.i1]
               + w10*pl[D.i1*GG+H.i0] + w11*pl[D.i1*GG+H.i1];
      const float* ll = dl + (p*CDEN + c)*GG;
      sigma += pv * (ll[D.i0] + fd*(ll[D.i1] - ll[D.i0]));
    }
    for (int c = 0; c < CAPP; c++){
      const float* pl = ap + (size_t)(p*CAPP + c)*GG*GG;
      float pv = w00*pl[D.i0*GG+H.i0] + w01*pl[D.i0*GG+H.i1]
               + w10*pl[D.i1*GG+H.i0] + w11*pl[D.i1*GG+H.i1];
      const float* ll = al + (p*CAPP + c)*GG;
      float ft = pv * (ll[D.i0] + fd*(ll[D.i1] - ll[D.i0]));
      int k = p*CAPP + c;
      for (int a = 0; a < ADIM; a++) acc[a] = fmaf(ft, W[a*KTOT + k], acc[a]);
    }
  }
  outv[n] = sigma;
  for (int a = 0; a < ADIM; a++) outv[NPTS + (size_t)n*ADIM + a] = acc[a];
}

extern "C" void kernel_launch(void* const* d_in, const int* in_sizes, int n_in,
                              void* d_out, int out_size, void* d_ws, size_t ws_size,
                              hipStream_t stream){
  const float* xyz    = (const float*)d_in[0];
  const float* dplane = (const float*)d_in[1];
  const float* dline  = (const float*)d_in[2];
  const float* aplane = (const float*)d_in[3];
  const float* aline  = (const float*)d_in[4];
  const float* W      = (const float*)d_in[5];
  float* outv = (float*)d_out;

  const size_t sz_dpt  = (size_t)3*GG*GG*CDEN*2;
  const size_t sz_apt  = (size_t)3*GG*GG*CAPP*2;
  const size_t sz_dlt  = (size_t)3*GG*CDEN*2;
  const size_t sz_alt  = (size_t)3*GG*CAPP*2;
  const size_t sz_bfr  = (size_t)3*2*2*64*16;
  const size_t sz_hist = (size_t)NBUCK*4;        // 614,400
  const size_t sz_offs = (size_t)NBUCK*4;
  const size_t sz_csum = (size_t)NCHUNK*4;
  const size_t sz_cbase= (size_t)NCHUNK*4;
  const size_t sz_keys = (size_t)NPTS*4;
  const size_t sz_xyzq = (size_t)NPTS*16;

  const size_t off_apt  = sz_dpt;
  const size_t off_dlt  = off_apt + sz_apt;
  const size_t off_alt  = off_dlt + sz_dlt;
  const size_t off_bfr  = off_alt + sz_alt;
  const size_t off_hist = off_bfr + sz_bfr;
  const size_t off_offs = off_hist + sz_hist;
  const size_t off_csum = off_offs + sz_offs;
  const size_t off_cbase= off_csum + sz_csum;
  const size_t off_keys = off_cbase + sz_cbase;
  const size_t off_xyzq = off_keys + sz_keys;
  const size_t need_tab  = off_hist;
  const size_t need_full = off_xyzq + sz_xyzq;

  if (ws_size < need_tab){
    sample_naive<<<(NPTS+255)/256, 256, 0, stream>>>(xyz, dplane, dline, aplane, aline, W, outv);
    return;
  }

  u16*   dpt = (u16*)((char*)d_ws);
  u16*   apt = (u16*)((char*)d_ws + off_apt);
  u16*   dlt = (u16*)((char*)d_ws + off_dlt);
  u16*   alt = (u16*)((char*)d_ws + off_alt);
  uint4* bfr = (uint4*)((char*)d_ws + off_bfr);

  if (ws_size < need_full){
    prep_all<<<2*TPBLK + 7, 256, 0, stream>>>(dplane, aplane, dline, aline, W, xyz,
                                              dpt, apt, dlt, alt, bfr, nullptr, nullptr);
    sample_mfma<false><<<NBLK64, 64, 0, stream>>>(nullptr, xyz, dpt, apt, dlt, alt, bfr, outv);
    return;
  }

  u32*    hist = (u32*)((char*)d_ws + off_hist);
  u32*    offs = (u32*)((char*)d_ws + off_offs);
  u32*    csum = (u32*)((char*)d_ws + off_csum);
  u32*    cbase= (u32*)((char*)d_ws + off_cbase);
  u32*    keys = (u32*)((char*)d_ws + off_keys);
  float4* xyzq = (float4*)((char*)d_ws + off_xyzq);

  hipMemsetAsync(hist, 0, sz_hist, stream);
  prep_all<<<2*TPBLK + 7 + NBLK, 256, 0, stream>>>(dplane, aplane, dline, aline, W, xyz,
                                                   dpt, apt, dlt, alt, bfr, hist, keys);
  scan1<<<NCHUNK, 1024, 0, stream>>>(hist, offs, csum);
  scan2<<<1, 256, 0, stream>>>(csum, cbase);
  scatter_pts<<<NBLK, 256, 0, stream>>>(xyz, keys, offs, cbase, xyzq);
  sample_mfma<true><<<NBLK64, 64, 0, stream>>>(xyzq, nullptr, dpt, apt, dlt, alt, bfr, outv);
}